// Round 2
// baseline (10932.851 us; speedup 1.0000x reference)
//
#include <hip/hip_runtime.h>
#include <hip/hip_bf16.h>
#include <math.h>

// Problem constants
#define NB    32    // batch
#define NSEED 128
#define NTT   512   // total timesteps (128 seed + 384 gen)
#define NIN   171
#define NINP  192   // padded input dim (6 k-tiles of 32)
#define NH    1024
#define NG    4096  // 4*H
#define NOUT  171
#define NOUTP 176   // padded to 11 n-tiles of 16
#define NWG   256

typedef unsigned short u16;
typedef unsigned int u32;
typedef __attribute__((ext_vector_type(8))) short bf16x8;
typedef __attribute__((ext_vector_type(4))) float f32x4;
typedef __attribute__((ext_vector_type(4))) int i32x4;

__device__ __host__ inline u16 f2bf(float x) {
  union { float f; unsigned u; } v; v.f = x;
  unsigned r = v.u + 0x7FFFu + ((v.u >> 16) & 1u);
  return (u16)(r >> 16);
}

// ---------------------------------------------------------------------------
// Packing kernels (unchanged)
// ---------------------------------------------------------------------------
__global__ void pack_mat(const float* __restrict__ src, u16* __restrict__ dst, int ktiles) {
  int id = blockIdx.x * 256 + threadIdx.x;
  int total = ktiles * 256 * 64;
  if (id >= total) return;
  int lane = id & 63;
  int nt = (id >> 6) & 255;
  int kt = id >> 14;
  int c = lane & 15, q = lane >> 4;
  int r = (c & 3) * 1024 + nt * 4 + (c >> 2);
  int K = ktiles * 32;
  const float* s = src + (size_t)r * K + kt * 32 + q * 8;
  __attribute__((aligned(16))) u16 o[8];
#pragma unroll
  for (int j = 0; j < 8; ++j) o[j] = f2bf(s[j]);
  *(bf16x8*)(dst + (size_t)id * 8) = *(const bf16x8*)o;
}

__global__ void pack_wih1(const float* __restrict__ src, u16* __restrict__ dst) {
  int id = blockIdx.x * 256 + threadIdx.x;
  if (id >= 6 * 256 * 64) return;
  int lane = id & 63;
  int nt = (id >> 6) & 255;
  int kt = id >> 14;
  int c = lane & 15, q = lane >> 4;
  int r = (c & 3) * 1024 + nt * 4 + (c >> 2);
  int k0 = kt * 32 + q * 8;
  __attribute__((aligned(16))) u16 o[8];
#pragma unroll
  for (int j = 0; j < 8; ++j) {
    int k = k0 + j;
    o[j] = (k < NIN) ? f2bf(src[(size_t)r * NIN + k]) : (u16)0;
  }
  *(bf16x8*)(dst + (size_t)id * 8) = *(const bf16x8*)o;
}

__global__ void pack_wdec(const float* __restrict__ src, u16* __restrict__ dst) {
  int id = blockIdx.x * 256 + threadIdx.x;
  if (id >= 32 * 11 * 64) return;
  int lane = id & 63;
  int nt = (id >> 6) % 11;
  int kt = (id >> 6) / 11;
  int c = lane & 15, q = lane >> 4;
  int r = nt * 16 + c;  // output column
  int k0 = kt * 32 + q * 8;
  __attribute__((aligned(16))) u16 o[8];
#pragma unroll
  for (int j = 0; j < 8; ++j) {
    o[j] = (r < NOUT) ? f2bf(src[(size_t)r * NH + k0 + j]) : (u16)0;
  }
  *(bf16x8*)(dst + (size_t)id * 8) = *(const bf16x8*)o;
}

__global__ void pack_seed(const float* __restrict__ src, u16* __restrict__ dst) {
  int id = blockIdx.x * 256 + threadIdx.x;
  if (id >= NSEED * NB * NINP) return;
  int kp = id % NINP;
  int b = (id / NINP) % NB;
  int t = id / (NINP * NB);
  float v = (kp < NIN) ? src[((size_t)b * NSEED + t) * NIN + kp] : 0.f;
  dst[id] = f2bf(v);
}

__global__ void wfuse_kernel(const float* __restrict__ wih1, const float* __restrict__ wdec,
                             float* __restrict__ tmp) {
  int n = blockIdx.x;
  int k = blockIdx.y * 256 + threadIdx.x;
  const float* wr = wih1 + (size_t)n * NIN;
  float s = 0.f;
  for (int i = 0; i < NIN; ++i) s += wr[i] * wdec[(size_t)i * NH + k];
  tmp[(size_t)n * NH + k] = s;
}

__global__ void prep_bias(const float* bih1, const float* bhh1, const float* bih2, const float* bhh2,
                          const float* bih3, const float* bhh3, const float* __restrict__ wih1,
                          const float* __restrict__ bdec_in,
                          float* b1s, float* b1g, float* b2, float* b3, float* bdecp,
                          int* __restrict__ flags, unsigned short* __restrict__ gflag) {
  int n = blockIdx.x * 256 + threadIdx.x;
  if (n >= NG) return;
  int wgi = n >> 4, c = n & 15;
  int r = (c & 3) * 1024 + wgi * 4 + (c >> 2);
  float v1 = bih1[r] + bhh1[r];
  b1s[n] = v1;
  float bf = 0.f;
  for (int i = 0; i < NIN; ++i) bf += wih1[(size_t)r * NIN + i] * bdec_in[i];
  b1g[n] = v1 + bf;
  b2[n] = bih2[r] + bhh2[r];
  b3[n] = bih3[r] + bhh3[r];
  if (n < NOUTP) bdecp[n] = (n < NOUT) ? bdec_in[n] : 0.f;
  if (n < NWG) flags[n] = 0;   // deterministic flag init
  if (n < 8) gflag[n] = 0;     // group-summary flags (one 16B line)
}

// ---------------------------------------------------------------------------
// Fast transcendentals on the pointwise critical path.
// ---------------------------------------------------------------------------
__device__ __forceinline__ float fsig(float x) {
  return __builtin_amdgcn_rcpf(1.f + __expf(-x));
}
__device__ __forceinline__ float ftanh(float x) {
  return 1.f - 2.f * __builtin_amdgcn_rcpf(1.f + __expf(2.f * x));
}

#define MFMA_BF16 __builtin_amdgcn_mfma_f32_16x16x32_bf16

// ---------------------------------------------------------------------------
// K=1024 matmul helpers. x is read with PLAIN cacheable loads: every (t,layer)
// h lives at a unique, write-once-per-dispatch address, first touched only
// after the flag barrier covering its producer (write-through-to-IF store), so
// no cache level can hold a stale copy within the dispatch; dispatch-boundary
// invalidation covers cross-launch reuse (previous rounds relied on it too).
// ---------------------------------------------------------------------------
__device__ __forceinline__ void mm32_lds(f32x4& d0, f32x4& d1, const u16* wl,
                                         const u16* __restrict__ x, int wv, int lane) {
  int m = lane & 15, q = lane >> 4;
  const u16* xa = x + m * NH + q * 8 + wv * 32;
  const u16* xb = xa + 16 * NH;
  const u16* wb = wl + lane * 8;
  bf16x8 w[8], a0[8], a1[8];
#pragma unroll
  for (int i = 0; i < 8; ++i) w[i] = *(const bf16x8*)(wb + (size_t)(wv + 4 * i) * 512);
#pragma unroll
  for (int i = 0; i < 8; ++i) {
    a0[i] = *(const bf16x8*)(xa + i * 128);
    a1[i] = *(const bf16x8*)(xb + i * 128);
  }
#pragma unroll
  for (int i = 0; i < 8; ++i) {
    d0 = MFMA_BF16(a0[i], w[i], d0, 0, 0, 0);
    d1 = MFMA_BF16(a1[i], w[i], d1, 0, 0, 0);
  }
}

__device__ __forceinline__ void mm32_glb(f32x4& d0, f32x4& d1, const u16* __restrict__ wgb,
                                         const u16* __restrict__ x, int wv, int lane) {
  int m = lane & 15, q = lane >> 4;
  const u16* xa = x + m * NH + q * 8 + wv * 32;
  const u16* xb = xa + 16 * NH;
  const u16* wb = wgb + lane * 8;
  bf16x8 w[8], a0[8], a1[8];
#pragma unroll
  for (int i = 0; i < 8; ++i) w[i] = *(const bf16x8*)(wb + (size_t)(wv + 4 * i) * 131072);
#pragma unroll
  for (int i = 0; i < 8; ++i) {
    a0[i] = *(const bf16x8*)(xa + i * 128);
    a1[i] = *(const bf16x8*)(xb + i * 128);
  }
#pragma unroll
  for (int i = 0; i < 8; ++i) {
    d0 = MFMA_BF16(a0[i], w[i], d0, 0, 0, 0);
    d1 = MFMA_BF16(a1[i], w[i], d1, 0, 0, 0);
  }
}

// K=192 (6 ktiles) seed-phase Wih1 path: both operands immutable -> cached.
__device__ __forceinline__ void mm6_glb(f32x4& d0, f32x4& d1, const u16* __restrict__ wbase,
                                        const u16* __restrict__ x, int wv, int lane) {
  int m = lane & 15, q = lane >> 4;
  const u16* xa = x + m * NINP + q * 8;
  const u16* xb = xa + 16 * NINP;
  const u16* wb = wbase + lane * 8;
#pragma unroll
  for (int i = 0; i < 2; ++i) {
    int kt = wv + 4 * i;
    if (kt >= 6) break;
    bf16x8 w = *(const bf16x8*)(wb + (size_t)kt * 131072);
    bf16x8 a0 = *(const bf16x8*)(xa + kt * 32);
    bf16x8 a1 = *(const bf16x8*)(xb + kt * 32);
    d0 = MFMA_BF16(a0, w, d0, 0, 0, 0);
    d1 = MFMA_BF16(a1, w, d1, 0, 0, 0);
  }
}

// ---------------------------------------------------------------------------
// Main persistent kernel. 256 WGs x 256 threads, 1 WG/CU.
//
// Barrier (changed this round): two-level hierarchical to kill the IF poll
// storm. 8 static groups of 32 WGs (blockIdx-based; correctness is mapping-
// independent since ALL flags are IF-scope):
//  - each WG stores its epoch to flags[wg] (relaxed agent, as before)
//  - group leader (wg%32==0) polls only its 32 member flags (2 lines),
//    then stores one u16 epoch into the shared 16-byte gflag line
//  - everyone polls gflag with a single wave-uniform dwordx4 (1 line)
// Poll traffic per sweep: ~270 line-reads vs ~4096 before (15x cut), so flag
// stores no longer queue behind the poll storm.
//
// Whh1 moved to LDS (4th slice): per-XCD L2 weight demand drops 3MB -> 2MB,
// eliminating the per-stage HBM weight refetch (the straggler source).
// ---------------------------------------------------------------------------
__global__ __launch_bounds__(256, 1) void lstm_main(
    const u16* __restrict__ whh1, const u16* __restrict__ whh2, const u16* __restrict__ whh3,
    const u16* __restrict__ wih2, const u16* __restrict__ wih3,
    const u16* __restrict__ wfuse, const u16* __restrict__ wih1,
    const u16* __restrict__ seedp,
    u16* __restrict__ h1h, u16* __restrict__ h2h, u16* __restrict__ h3h,
    const float* __restrict__ b1s, const float* __restrict__ b1g,
    const float* __restrict__ b2, const float* __restrict__ b3,
    int* __restrict__ flags, unsigned short* __restrict__ gflag)
{
  __shared__ u16  wlds[4 * 16384];     // 128 KB: wih2 | wih3 | wfuse | whh1
  __shared__ float red[4][64][8];      // 4-wave split-K reduction (8 KB)
  __shared__ float gbuf[32][16];       // gates (b, packed col)
  __shared__ float cst[3][32][4];      // cell state: layer, batch, local j

  int wg = blockIdx.x;
  int tid = threadIdx.x;
  int wv = tid >> 6, lane = tid & 63;
  int grp = wg >> 5;
  bool islead = (wg & 31) == 0;
  int grpbase = wg & ~31;

  // ---- stage weight slices into LDS (one time) ----
  {
    const u16* srcs[4] = { wih2 + (size_t)wg * 512, wih3 + (size_t)wg * 512,
                           wfuse + (size_t)wg * 512, whh1 + (size_t)wg * 512 };
#pragma unroll
    for (int m = 0; m < 4; ++m) {
      for (int i = tid; i < 2048; i += 256) {          // 32 kt * 64 lanes
        int kt = i >> 6, ln = i & 63;
        *(bf16x8*)&wlds[m * 16384 + (kt * 64 + ln) * 8] =
            *(const bf16x8*)(srcs[m] + ((size_t)kt * 16384 + ln) * 8);
      }
    }
    float* cp = &cst[0][0][0];
    for (int i = tid; i < 3 * 32 * 4; i += 256) cp[i] = 0.f;
  }
  __syncthreads();

  // per-thread bias preload (epilogue uses c = tid & 15)
  int c0 = tid & 15;
  float bv_s  = b1s[wg * 16 + c0];
  float bv_g  = b1g[wg * 16 + c0];
  float bv_2  = b2 [wg * 16 + c0];
  float bv_3  = b3 [wg * 16 + c0];

  const u16* whh2g = whh2 + (size_t)wg * 512;
  const u16* whh3g = whh3 + (size_t)wg * 512;
  const u16* wih1g = wih1 + (size_t)wg * 512;

  int ep = 0;  // completed stages
  for (int t = 0; t < NTT; ++t) {
    for (int l = 0; l < 3; ++l) {
      f32x4 d0 = {0.f, 0.f, 0.f, 0.f}, d1 = {0.f, 0.f, 0.f, 0.f};
      bool isseed = (t < NSEED);

      // ---- pre-barrier work (inputs covered by waits already passed) ----
      if (l == 0 && isseed)
        mm6_glb(d0, d1, wih1g, seedp + (size_t)t * NB * NINP, wv, lane);
      if (t > 0) {            // recurrent term h_l[t-1] @ Whh_l^T
        if (l == 0)
          mm32_lds(d0, d1, &wlds[3 * 16384], h1h + (size_t)(t - 1) * NB * NH, wv, lane);
        else if (l == 1)
          mm32_glb(d0, d1, whh2g, h2h + (size_t)(t - 1) * NB * NH, wv, lane);
        else
          mm32_glb(d0, d1, whh3g, h3h + (size_t)(t - 1) * NB * NH, wv, lane);
      }

      // ---- hierarchical grid barrier wait (skip: seed-phase l==0) ----
      bool skipwait = (l == 0 && isseed);
      if (ep > 0 && !skipwait) {
        if (tid < 64) {
          if (islead) {
            const int* fp = flags + grpbase;
            for (;;) {
              int f = (tid < 32)
                  ? __hip_atomic_load(fp + tid, __ATOMIC_RELAXED, __HIP_MEMORY_SCOPE_AGENT)
                  : ep;
              if (__all(f >= ep)) break;
              __builtin_amdgcn_s_sleep(1);
            }
            if (tid == 0)
              __hip_atomic_store(gflag + grp, (unsigned short)ep,
                                 __ATOMIC_RELAXED, __HIP_MEMORY_SCOPE_AGENT);
          }
          for (;;) {
            i32x4 g;
            asm volatile("global_load_dwordx4 %0, %1, off sc0 sc1\n\ts_waitcnt vmcnt(0)"
                         : "=v"(g) : "v"(gflag) : "memory");
            unsigned m0 = min(min((unsigned)(g.x & 0xFFFF), ((unsigned)g.x) >> 16),
                              min((unsigned)(g.y & 0xFFFF), ((unsigned)g.y) >> 16));
            unsigned m1 = min(min((unsigned)(g.z & 0xFFFF), ((unsigned)g.z) >> 16),
                              min((unsigned)(g.w & 0xFFFF), ((unsigned)g.w) >> 16));
            if (min(m0, m1) >= (unsigned)ep) break;
            __builtin_amdgcn_s_sleep(1);
          }
        }
        __syncthreads();
      }

      // ---- post-barrier: fresh input term (B from LDS, x first-touch) ----
      if (l == 0) {
        if (!isseed)
          mm32_lds(d0, d1, &wlds[2 * 16384], h3h + (size_t)(t - 1) * NB * NH, wv, lane);
      } else {
        const u16* xs = (l == 1) ? h1h + (size_t)t * NB * NH
                                 : h2h + (size_t)t * NB * NH;
        mm32_lds(d0, d1, &wlds[(l - 1) * 16384], xs, wv, lane);
      }

      // ---- reduce the 4 waves' split-K partials via LDS ----
#pragma unroll
      for (int r = 0; r < 4; ++r) { red[wv][lane][r] = d0[r]; red[wv][lane][4 + r] = d1[r]; }
      __syncthreads();
      {
        int c = tid & 15, brow = tid >> 4;   // brow 0..15
        float bv = (l == 0) ? (isseed ? bv_s : bv_g) : (l == 1) ? bv_2 : bv_3;
        int srcl = ((brow >> 2) << 4) | c;   // D-frag: col=lane&15, row=(lane>>4)*4+reg
#pragma unroll
        for (int mt = 0; mt < 2; ++mt) {
          int b = brow + mt * 16;
          int idx = mt * 4 + (brow & 3);
          gbuf[b][c] = red[0][srcl][idx] + red[1][srcl][idx] +
                       red[2][srcl][idx] + red[3][srcl][idx] + bv;
        }
      }
      __syncthreads();

      // ---- pointwise LSTM cell; h exchange via relaxed agent u32 stores ----
      if (tid < 128) {
        int b = tid & 31, jl = tid >> 5;
        float gi = gbuf[b][jl * 4 + 0], gf = gbuf[b][jl * 4 + 1];
        float gg = gbuf[b][jl * 4 + 2], go = gbuf[b][jl * 4 + 3];
        float si = fsig(gi);
        float sf = fsig(gf);
        float so = fsig(go);
        float cn = sf * cst[l][b][jl] + si * ftanh(gg);
        cst[l][b][jl] = cn;
        float hn = so * ftanh(cn);
        unsigned hv = (unsigned)f2bf(hn);
        // pair (jl even, jl odd) lives at lane ^ 32 within the same wave
        unsigned other = (unsigned)__shfl_xor((int)hv, 32, 64);
        if (lane < 32) {
          unsigned val = hv | (other << 16);
          int w01 = tid >> 6;  // 0 -> cols (0,1), 1 -> cols (2,3)
          u16* hdst = (l == 0) ? h1h + (size_t)t * NB * NH
                    : (l == 1) ? h2h + (size_t)t * NB * NH
                               : h3h + (size_t)t * NB * NH;
          u32* hp = (u32*)hdst + (size_t)b * 512 + wg * 2 + w01;
          __hip_atomic_store(hp, val, __ATOMIC_RELAXED, __HIP_MEMORY_SCOPE_AGENT);
        }
      }

      // ---- signal stage completion (relaxed; syncthreads drained vmcnt) ----
      __syncthreads();
      ++ep;
      if (tid == 0)
        __hip_atomic_store(&flags[wg], ep, __ATOMIC_RELAXED, __HIP_MEMORY_SCOPE_AGENT);
    }
  }
}

// ---------------------------------------------------------------------------
// Batched decoder: out[b][t][o] = h3[t] @ Wdec^T + bdec for all 512 steps.
// ---------------------------------------------------------------------------
__global__ __launch_bounds__(256) void dec_kernel(
    const u16* __restrict__ h3h, const u16* __restrict__ wdec,
    const float* __restrict__ bdecp, float* __restrict__ out)
{
  int task = blockIdx.x * 4 + (threadIdx.x >> 6);
  int lane = threadIdx.x & 63;
  int nt = task % 11, rt = task / 11;
  if (rt >= NTT) return;
  int m = lane & 15, q = lane >> 4;
  const u16* xa = h3h + ((size_t)rt * 32 + m) * NH + q * 8;
  const u16* xb = xa + (size_t)16 * NH;
  f32x4 d0 = {0.f, 0.f, 0.f, 0.f}, d1 = {0.f, 0.f, 0.f, 0.f};
  for (int kt = 0; kt < 32; ++kt) {
    bf16x8 bf = *(const bf16x8*)(wdec + ((size_t)(kt * 11 + nt) * 64 + lane) * 8);
    bf16x8 a0 = *(const bf16x8*)(xa + kt * 32);
    bf16x8 a1 = *(const bf16x8*)(xb + kt * 32);
    d0 = MFMA_BF16(a0, bf, d0, 0, 0, 0);
    d1 = MFMA_BF16(a1, bf, d1, 0, 0, 0);
  }
  int o = nt * 16 + m;
  if (o >= NOUT) return;
  float bv = bdecp[o];
#pragma unroll
  for (int reg = 0; reg < 4; ++reg) {
    int row0 = rt * 32 + q * 4 + reg;          // row = t*32 + b
    out[(((size_t)(row0 & 31)) * NTT + (row0 >> 5)) * NOUT + o] = d0[reg] + bv;
    int row1 = row0 + 16;
    out[(((size_t)(row1 & 31)) * NTT + (row1 >> 5)) * NOUT + o] = d1[reg] + bv;
  }
}

// ---------------------------------------------------------------------------
extern "C" void kernel_launch(void* const* d_in, const int* in_sizes, int n_in,
                              void* d_out, int out_size, void* d_ws, size_t ws_size,
                              hipStream_t stream) {
  const float* seed = (const float*)d_in[0];
  const float* Wih1 = (const float*)d_in[1];
  const float* Whh1 = (const float*)d_in[2];
  const float* bih1 = (const float*)d_in[3];
  const float* bhh1 = (const float*)d_in[4];
  const float* Wih2 = (const float*)d_in[5];
  const float* Whh2 = (const float*)d_in[6];
  const float* bih2 = (const float*)d_in[7];
  const float* bhh2 = (const float*)d_in[8];
  const float* Wih3 = (const float*)d_in[9];
  const float* Whh3 = (const float*)d_in[10];
  const float* bih3 = (const float*)d_in[11];
  const float* bhh3 = (const float*)d_in[12];
  const float* Wdec = (const float*)d_in[13];
  const float* bdec = (const float*)d_in[14];

  char* ws = (char*)d_ws;
  size_t off = 0;
  auto alloc = [&](size_t bytes) -> void* {
    void* p = ws + off;
    off += (bytes + 63) & ~(size_t)63;
    return p;
  };
  const size_t BIGPK = (size_t)32 * 256 * 64 * 8 * 2;  // 8.39 MB each
  const size_t HHIST = (size_t)NTT * NB * NH * 2;      // 33.55 MB per layer
  u16* whh1p  = (u16*)alloc(BIGPK);
  u16* whh2p  = (u16*)alloc(BIGPK);
  u16* whh3p  = (u16*)alloc(BIGPK);
  u16* wih2p  = (u16*)alloc(BIGPK);
  u16* wih3p  = (u16*)alloc(BIGPK);
  u16* wfusep = (u16*)alloc(BIGPK);
  u16* wih1p  = (u16*)alloc((size_t)6 * 256 * 64 * 8 * 2);
  u16* wdecp  = (u16*)alloc((size_t)32 * 11 * 64 * 8 * 2);
  u16* seedp  = (u16*)alloc((size_t)NSEED * NB * NINP * 2);
  u16* h1h    = (u16*)alloc(HHIST);                    // write-once per (t)
  u16* h2h    = (u16*)alloc(HHIST);                    // write-once per (t)
  u16* h3h    = (u16*)alloc(HHIST);                    // write-once per (t)
  float* b1s  = (float*)alloc((size_t)NG * 4);
  float* b1g  = (float*)alloc((size_t)NG * 4);
  float* b2   = (float*)alloc((size_t)NG * 4);
  float* b3   = (float*)alloc((size_t)NG * 4);
  float* bdecp = (float*)alloc((size_t)NOUTP * 4);
  int* flags  = (int*)alloc((size_t)NWG * 4);
  unsigned short* gflag = (unsigned short*)alloc(64); // 8 x u16 group epochs
  // Wfuse fp32 temp aliases h3h (prep finishes before lstm_main writes h3h,
  // and lstm_main fully rewrites h3h before any in-kernel/dec read of it).
  float* wftmp = (float*)h3h;

  // ---- prep ----
  pack_mat<<<dim3(2048), dim3(256), 0, stream>>>(Whh1, whh1p, 32);
  pack_mat<<<dim3(2048), dim3(256), 0, stream>>>(Whh2, whh2p, 32);
  pack_mat<<<dim3(2048), dim3(256), 0, stream>>>(Whh3, whh3p, 32);
  pack_mat<<<dim3(2048), dim3(256), 0, stream>>>(Wih2, wih2p, 32);
  pack_mat<<<dim3(2048), dim3(256), 0, stream>>>(Wih3, wih3p, 32);
  pack_wih1<<<dim3(384), dim3(256), 0, stream>>>(Wih1, wih1p);
  wfuse_kernel<<<dim3(4096, 4), dim3(256), 0, stream>>>(Wih1, Wdec, wftmp);
  pack_mat<<<dim3(2048), dim3(256), 0, stream>>>(wftmp, wfusep, 32);
  pack_wdec<<<dim3(88), dim3(256), 0, stream>>>(Wdec, wdecp);
  pack_seed<<<dim3(3072), dim3(256), 0, stream>>>(seed, seedp);
  prep_bias<<<dim3(16), dim3(256), 0, stream>>>(bih1, bhh1, bih2, bhh2, bih3, bhh3,
                                                Wih1, bdec, b1s, b1g, b2, b3, bdecp,
                                                flags, gflag);
  // ---- recurrence ----
  lstm_main<<<dim3(NWG), dim3(256), 0, stream>>>(
      whh1p, whh2p, whh3p, wih2p, wih3p, wfusep, wih1p, seedp,
      h1h, h2h, h3h, b1s, b1g, b2, b3, flags, gflag);
  // ---- batched decoder ----
  dec_kernel<<<dim3(1408), dim3(256), 0, stream>>>(h3h, wdecp, bdecp, (float*)d_out);
}

// Round 3
// 6706.413 us; speedup vs baseline: 1.6302x; 1.6302x over previous
//
#include <hip/hip_runtime.h>
#include <hip/hip_bf16.h>
#include <math.h>

// Problem constants
#define NB    32    // batch
#define NSEED 128
#define NTT   512   // total timesteps (128 seed + 384 gen)
#define NIN   171
#define NINP  192   // padded input dim (6 k-tiles of 32)
#define NH    1024
#define NG    4096  // 4*H
#define NOUT  171
#define NOUTP 176   // padded to 11 n-tiles of 16
#define NWG   256

typedef unsigned short u16;
typedef unsigned int u32;
typedef __attribute__((ext_vector_type(8))) short bf16x8;
typedef __attribute__((ext_vector_type(4))) float f32x4;
typedef __attribute__((ext_vector_type(4))) int i32x4;

__device__ __host__ inline u16 f2bf(float x) {
  union { float f; unsigned u; } v; v.f = x;
  unsigned r = v.u + 0x7FFFu + ((v.u >> 16) & 1u);
  return (u16)(r >> 16);
}

// ---------------------------------------------------------------------------
// Packing kernels (unchanged)
// ---------------------------------------------------------------------------
__global__ void pack_mat(const float* __restrict__ src, u16* __restrict__ dst, int ktiles) {
  int id = blockIdx.x * 256 + threadIdx.x;
  int total = ktiles * 256 * 64;
  if (id >= total) return;
  int lane = id & 63;
  int nt = (id >> 6) & 255;
  int kt = id >> 14;
  int c = lane & 15, q = lane >> 4;
  int r = (c & 3) * 1024 + nt * 4 + (c >> 2);
  int K = ktiles * 32;
  const float* s = src + (size_t)r * K + kt * 32 + q * 8;
  __attribute__((aligned(16))) u16 o[8];
#pragma unroll
  for (int j = 0; j < 8; ++j) o[j] = f2bf(s[j]);
  *(bf16x8*)(dst + (size_t)id * 8) = *(const bf16x8*)o;
}

__global__ void pack_wih1(const float* __restrict__ src, u16* __restrict__ dst) {
  int id = blockIdx.x * 256 + threadIdx.x;
  if (id >= 6 * 256 * 64) return;
  int lane = id & 63;
  int nt = (id >> 6) & 255;
  int kt = id >> 14;
  int c = lane & 15, q = lane >> 4;
  int r = (c & 3) * 1024 + nt * 4 + (c >> 2);
  int k0 = kt * 32 + q * 8;
  __attribute__((aligned(16))) u16 o[8];
#pragma unroll
  for (int j = 0; j < 8; ++j) {
    int k = k0 + j;
    o[j] = (k < NIN) ? f2bf(src[(size_t)r * NIN + k]) : (u16)0;
  }
  *(bf16x8*)(dst + (size_t)id * 8) = *(const bf16x8*)o;
}

__global__ void pack_wdec(const float* __restrict__ src, u16* __restrict__ dst) {
  int id = blockIdx.x * 256 + threadIdx.x;
  if (id >= 32 * 11 * 64) return;
  int lane = id & 63;
  int nt = (id >> 6) % 11;
  int kt = (id >> 6) / 11;
  int c = lane & 15, q = lane >> 4;
  int r = nt * 16 + c;  // output column
  int k0 = kt * 32 + q * 8;
  __attribute__((aligned(16))) u16 o[8];
#pragma unroll
  for (int j = 0; j < 8; ++j) {
    o[j] = (r < NOUT) ? f2bf(src[(size_t)r * NH + k0 + j]) : (u16)0;
  }
  *(bf16x8*)(dst + (size_t)id * 8) = *(const bf16x8*)o;
}

__global__ void pack_seed(const float* __restrict__ src, u16* __restrict__ dst) {
  int id = blockIdx.x * 256 + threadIdx.x;
  if (id >= NSEED * NB * NINP) return;
  int kp = id % NINP;
  int b = (id / NINP) % NB;
  int t = id / (NINP * NB);
  float v = (kp < NIN) ? src[((size_t)b * NSEED + t) * NIN + kp] : 0.f;
  dst[id] = f2bf(v);
}

__global__ void wfuse_kernel(const float* __restrict__ wih1, const float* __restrict__ wdec,
                             float* __restrict__ tmp) {
  int n = blockIdx.x;
  int k = blockIdx.y * 256 + threadIdx.x;
  const float* wr = wih1 + (size_t)n * NIN;
  float s = 0.f;
  for (int i = 0; i < NIN; ++i) s += wr[i] * wdec[(size_t)i * NH + k];
  tmp[(size_t)n * NH + k] = s;
}

__global__ void prep_bias(const float* bih1, const float* bhh1, const float* bih2, const float* bhh2,
                          const float* bih3, const float* bhh3, const float* __restrict__ wih1,
                          const float* __restrict__ bdec_in,
                          float* b1s, float* b1g, float* b2, float* b3, float* bdecp,
                          int* __restrict__ flags) {
  int n = blockIdx.x * 256 + threadIdx.x;
  if (n >= NG) return;
  int wgi = n >> 4, c = n & 15;
  int r = (c & 3) * 1024 + wgi * 4 + (c >> 2);
  float v1 = bih1[r] + bhh1[r];
  b1s[n] = v1;
  float bf = 0.f;
  for (int i = 0; i < NIN; ++i) bf += wih1[(size_t)r * NIN + i] * bdec_in[i];
  b1g[n] = v1 + bf;
  b2[n] = bih2[r] + bhh2[r];
  b3[n] = bih3[r] + bhh3[r];
  if (n < NOUTP) bdecp[n] = (n < NOUT) ? bdec_in[n] : 0.f;
  if (n < NWG) flags[n] = 0;   // deterministic flag init
}

// ---------------------------------------------------------------------------
// Fast transcendentals on the pointwise critical path.
// ---------------------------------------------------------------------------
__device__ __forceinline__ float fsig(float x) {
  return __builtin_amdgcn_rcpf(1.f + __expf(-x));
}
__device__ __forceinline__ float ftanh(float x) {
  return 1.f - 2.f * __builtin_amdgcn_rcpf(1.f + __expf(2.f * x));
}

#define MFMA_BF16 __builtin_amdgcn_mfma_f32_16x16x32_bf16

// ---------------------------------------------------------------------------
// K=1024 matmul helpers. x is read with PLAIN cacheable loads: every (t,layer)
// h lives at a unique, write-once-per-dispatch address, first touched only
// after the flag barrier covering its producer (write-through-to-IF store), so
// no cache level can hold a stale copy within the dispatch. a-loads (long
// latency, IF) are issued BEFORE w-loads.
// ---------------------------------------------------------------------------
__device__ __forceinline__ void mm32_lds(f32x4& d0, f32x4& d1, const u16* wl,
                                         const u16* __restrict__ x, int wv, int lane) {
  int m = lane & 15, q = lane >> 4;
  const u16* xa = x + m * NH + q * 8 + wv * 32;
  const u16* xb = xa + 16 * NH;
  const u16* wb = wl + lane * 8;
  bf16x8 w[8], a0[8], a1[8];
#pragma unroll
  for (int i = 0; i < 8; ++i) {
    a0[i] = *(const bf16x8*)(xa + i * 128);
    a1[i] = *(const bf16x8*)(xb + i * 128);
  }
#pragma unroll
  for (int i = 0; i < 8; ++i) w[i] = *(const bf16x8*)(wb + (size_t)(wv + 4 * i) * 512);
#pragma unroll
  for (int i = 0; i < 8; ++i) {
    d0 = MFMA_BF16(a0[i], w[i], d0, 0, 0, 0);
    d1 = MFMA_BF16(a1[i], w[i], d1, 0, 0, 0);
  }
}

__device__ __forceinline__ void mm32_glb(f32x4& d0, f32x4& d1, const u16* __restrict__ wgb,
                                         const u16* __restrict__ x, int wv, int lane) {
  int m = lane & 15, q = lane >> 4;
  const u16* xa = x + m * NH + q * 8 + wv * 32;
  const u16* xb = xa + 16 * NH;
  const u16* wb = wgb + lane * 8;
  bf16x8 w[8], a0[8], a1[8];
#pragma unroll
  for (int i = 0; i < 8; ++i) {
    a0[i] = *(const bf16x8*)(xa + i * 128);
    a1[i] = *(const bf16x8*)(xb + i * 128);
  }
#pragma unroll
  for (int i = 0; i < 8; ++i) w[i] = *(const bf16x8*)(wb + (size_t)(wv + 4 * i) * 131072);
#pragma unroll
  for (int i = 0; i < 8; ++i) {
    d0 = MFMA_BF16(a0[i], w[i], d0, 0, 0, 0);
    d1 = MFMA_BF16(a1[i], w[i], d1, 0, 0, 0);
  }
}

// K=192 (6 ktiles) seed-phase Wih1 path: both operands immutable -> cached.
__device__ __forceinline__ void mm6_glb(f32x4& d0, f32x4& d1, const u16* __restrict__ wbase,
                                        const u16* __restrict__ x, int wv, int lane) {
  int m = lane & 15, q = lane >> 4;
  const u16* xa = x + m * NINP + q * 8;
  const u16* xb = xa + 16 * NINP;
  const u16* wb = wbase + lane * 8;
#pragma unroll
  for (int i = 0; i < 2; ++i) {
    int kt = wv + 4 * i;
    if (kt >= 6) break;
    bf16x8 w = *(const bf16x8*)(wb + (size_t)kt * 131072);
    bf16x8 a0 = *(const bf16x8*)(xa + kt * 32);
    bf16x8 a1 = *(const bf16x8*)(xb + kt * 32);
    d0 = MFMA_BF16(a0, w, d0, 0, 0, 0);
    d1 = MFMA_BF16(a1, w, d1, 0, 0, 0);
  }
}

// ---------------------------------------------------------------------------
// Main persistent kernel. 256 WGs x 256 threads, 1 WG/CU.
//
// Barrier: FLAT single-hop (R1's hierarchical version added a serial hop and
// regressed). Each WG stores its epoch flag (relaxed agent, IF-scope); wave 1
// polls all 256 flags with one dwordx4 per lane.
//
// Epilogue (changed this round): single-wave fused epilogue. Wave 0 alone does
// gather+pointwise+h-store (2 cells/lane, no gbuf, no cross-wave shfl), drains
// its OWN stores with s_waitcnt vmcnt(0), stores the flag. No full-WG barrier
// between the last MFMA partials and the flag. Waves 1-3 immediately start the
// next stage's pre-barrier recurrent GEMM; wave 1 polls while wave 0 finishes.
// Red-buffer safety: waves 1-3's next red-write happens only after sync(A) of
// the next stage, which wave 0 joins only after its red-reads are done.
// ---------------------------------------------------------------------------
__global__ __launch_bounds__(256, 1) void lstm_main(
    const u16* __restrict__ whh1, const u16* __restrict__ whh2, const u16* __restrict__ whh3,
    const u16* __restrict__ wih2, const u16* __restrict__ wih3,
    const u16* __restrict__ wfuse, const u16* __restrict__ wih1,
    const u16* __restrict__ seedp,
    u16* __restrict__ h1h, u16* __restrict__ h2h, u16* __restrict__ h3h,
    const float* __restrict__ b1s, const float* __restrict__ b1g,
    const float* __restrict__ b2, const float* __restrict__ b3,
    int* __restrict__ flags)
{
  __shared__ u16  wlds[4 * 16384];     // 128 KB: wih2 | wih3 | wfuse | whh1
  __shared__ float red[4][64][8];      // 4-wave split-K reduction (8 KB)
  __shared__ float biasLds[4][16];     // b1s | b1g | b2 | b3 slices
  __shared__ float cst[3][32][4];      // cell state: layer, batch, unit

  int wg = blockIdx.x;
  int tid = threadIdx.x;
  int wv = tid >> 6, lane = tid & 63;

  // ---- stage weight slices into LDS (one time) ----
  {
    const u16* srcs[4] = { wih2 + (size_t)wg * 512, wih3 + (size_t)wg * 512,
                           wfuse + (size_t)wg * 512, whh1 + (size_t)wg * 512 };
#pragma unroll
    for (int m = 0; m < 4; ++m) {
      for (int i = tid; i < 2048; i += 256) {          // 32 kt * 64 lanes
        int kt = i >> 6, ln = i & 63;
        *(bf16x8*)&wlds[m * 16384 + (kt * 64 + ln) * 8] =
            *(const bf16x8*)(srcs[m] + ((size_t)kt * 16384 + ln) * 8);
      }
    }
    float* cp = &cst[0][0][0];
    for (int i = tid; i < 3 * 32 * 4; i += 256) cp[i] = 0.f;
    if (tid < 64) {
      int row = tid >> 4, c = tid & 15;
      const float* src = (row == 0) ? b1s : (row == 1) ? b1g : (row == 2) ? b2 : b3;
      biasLds[row][c] = src[wg * 16 + c];
    }
  }
  __syncthreads();

  const u16* whh2g = whh2 + (size_t)wg * 512;
  const u16* whh3g = whh3 + (size_t)wg * 512;
  const u16* wih1g = wih1 + (size_t)wg * 512;

  int ep = 0;  // completed stages
  for (int t = 0; t < NTT; ++t) {
    for (int l = 0; l < 3; ++l) {
      f32x4 d0 = {0.f, 0.f, 0.f, 0.f}, d1 = {0.f, 0.f, 0.f, 0.f};
      bool isseed = (t < NSEED);

      // ---- pre-barrier work (inputs covered by waits already passed) ----
      if (l == 0 && isseed)
        mm6_glb(d0, d1, wih1g, seedp + (size_t)t * NB * NINP, wv, lane);
      if (t > 0) {            // recurrent term h_l[t-1] @ Whh_l^T
        if (l == 0)
          mm32_lds(d0, d1, &wlds[3 * 16384], h1h + (size_t)(t - 1) * NB * NH, wv, lane);
        else if (l == 1)
          mm32_glb(d0, d1, whh2g, h2h + (size_t)(t - 1) * NB * NH, wv, lane);
        else
          mm32_glb(d0, d1, whh3g, h3h + (size_t)(t - 1) * NB * NH, wv, lane);
      }

      // ---- flat grid barrier: wave 1 polls; sync(A) always ----
      bool skipwait = (l == 0 && isseed);
      if (ep > 0 && !skipwait && wv == 1) {
        const int* fp = flags + (lane << 2);
        for (;;) {
          i32x4 f;
          asm volatile("global_load_dwordx4 %0, %1, off sc0 sc1\n\ts_waitcnt vmcnt(0)"
                       : "=v"(f) : "v"(fp) : "memory");
          int mn = min(min(f.x, f.y), min(f.z, f.w));
          if (__all(mn >= ep)) break;
          __builtin_amdgcn_s_sleep(1);
        }
      }
      __syncthreads();   // (A)

      // ---- post-barrier: fresh input term (B from LDS, x first-touch) ----
      if (l == 0) {
        if (!isseed)
          mm32_lds(d0, d1, &wlds[2 * 16384], h3h + (size_t)(t - 1) * NB * NH, wv, lane);
      } else {
        const u16* xs = (l == 1) ? h1h + (size_t)t * NB * NH
                                 : h2h + (size_t)t * NB * NH;
        mm32_lds(d0, d1, &wlds[(l - 1) * 16384], xs, wv, lane);
      }

      // ---- publish split-K partials ----
#pragma unroll
      for (int r = 0; r < 4; ++r) { red[wv][lane][r] = d0[r]; red[wv][lane][4 + r] = d1[r]; }
      __syncthreads();   // (B)

      int epn = ep + 1;
      // ---- wave-0 fused epilogue; waves 1-3 run ahead to next pre-mm ----
      if (tid < 64) {
        __builtin_amdgcn_s_setprio(1);
        int b = tid & 31, upair = tid >> 5;
        int srcl_base = ((b & 15) >> 2) << 4;
        int idx = ((b >> 4) << 2) | (b & 3);
        int bsel = (l == 0) ? (isseed ? 0 : 1) : (l + 1);
        float g[8];
#pragma unroll
        for (int u2 = 0; u2 < 2; ++u2) {
          int u = upair * 2 + u2;
#pragma unroll
          for (int gi = 0; gi < 4; ++gi) {
            int c = u * 4 + gi;
            int srcl = srcl_base | c;
            g[u2 * 4 + gi] = red[0][srcl][idx] + red[1][srcl][idx] +
                             red[2][srcl][idx] + red[3][srcl][idx] + biasLds[bsel][c];
          }
        }
        unsigned hv[2];
#pragma unroll
        for (int u2 = 0; u2 < 2; ++u2) {
          int u = upair * 2 + u2;
          float si = fsig(g[u2 * 4 + 0]);
          float sf = fsig(g[u2 * 4 + 1]);
          float so = fsig(g[u2 * 4 + 3]);
          float cn = sf * cst[l][b][u] + si * ftanh(g[u2 * 4 + 2]);
          cst[l][b][u] = cn;
          hv[u2] = (unsigned)f2bf(so * ftanh(cn));
        }
        unsigned val = hv[0] | (hv[1] << 16);
        u16* hdst = (l == 0) ? h1h + (size_t)t * NB * NH
                  : (l == 1) ? h2h + (size_t)t * NB * NH
                             : h3h + (size_t)t * NB * NH;
        u32* hp = (u32*)hdst + (size_t)b * 512 + wg * 2 + upair;
        __hip_atomic_store(hp, val, __ATOMIC_RELAXED, __HIP_MEMORY_SCOPE_AGENT);
        asm volatile("s_waitcnt vmcnt(0)" ::: "memory");   // own-store drain only
        if (tid == 0)
          __hip_atomic_store(&flags[wg], epn, __ATOMIC_RELAXED, __HIP_MEMORY_SCOPE_AGENT);
        __builtin_amdgcn_s_setprio(0);
      }
      ep = epn;
    }
  }
}

// ---------------------------------------------------------------------------
// Batched decoder: out[b][t][o] = h3[t] @ Wdec^T + bdec for all 512 steps.
// ---------------------------------------------------------------------------
__global__ __launch_bounds__(256) void dec_kernel(
    const u16* __restrict__ h3h, const u16* __restrict__ wdec,
    const float* __restrict__ bdecp, float* __restrict__ out)
{
  int task = blockIdx.x * 4 + (threadIdx.x >> 6);
  int lane = threadIdx.x & 63;
  int nt = task % 11, rt = task / 11;
  if (rt >= NTT) return;
  int m = lane & 15, q = lane >> 4;
  const u16* xa = h3h + ((size_t)rt * 32 + m) * NH + q * 8;
  const u16* xb = xa + (size_t)16 * NH;
  f32x4 d0 = {0.f, 0.f, 0.f, 0.f}, d1 = {0.f, 0.f, 0.f, 0.f};
  for (int kt = 0; kt < 32; ++kt) {
    bf16x8 bf = *(const bf16x8*)(wdec + ((size_t)(kt * 11 + nt) * 64 + lane) * 8);
    bf16x8 a0 = *(const bf16x8*)(xa + kt * 32);
    bf16x8 a1 = *(const bf16x8*)(xb + kt * 32);
    d0 = MFMA_BF16(a0, bf, d0, 0, 0, 0);
    d1 = MFMA_BF16(a1, bf, d1, 0, 0, 0);
  }
  int o = nt * 16 + m;
  if (o >= NOUT) return;
  float bv = bdecp[o];
#pragma unroll
  for (int reg = 0; reg < 4; ++reg) {
    int row0 = rt * 32 + q * 4 + reg;          // row = t*32 + b
    out[(((size_t)(row0 & 31)) * NTT + (row0 >> 5)) * NOUT + o] = d0[reg] + bv;
    int row1 = row0 + 16;
    out[(((size_t)(row1 & 31)) * NTT + (row1 >> 5)) * NOUT + o] = d1[reg] + bv;
  }
}

// ---------------------------------------------------------------------------
extern "C" void kernel_launch(void* const* d_in, const int* in_sizes, int n_in,
                              void* d_out, int out_size, void* d_ws, size_t ws_size,
                              hipStream_t stream) {
  const float* seed = (const float*)d_in[0];
  const float* Wih1 = (const float*)d_in[1];
  const float* Whh1 = (const float*)d_in[2];
  const float* bih1 = (const float*)d_in[3];
  const float* bhh1 = (const float*)d_in[4];
  const float* Wih2 = (const float*)d_in[5];
  const float* Whh2 = (const float*)d_in[6];
  const float* bih2 = (const float*)d_in[7];
  const float* bhh2 = (const float*)d_in[8];
  const float* Wih3 = (const float*)d_in[9];
  const float* Whh3 = (const float*)d_in[10];
  const float* bih3 = (const float*)d_in[11];
  const float* bhh3 = (const float*)d_in[12];
  const float* Wdec = (const float*)d_in[13];
  const float* bdec = (const float*)d_in[14];

  char* ws = (char*)d_ws;
  size_t off = 0;
  auto alloc = [&](size_t bytes) -> void* {
    void* p = ws + off;
    off += (bytes + 63) & ~(size_t)63;
    return p;
  };
  const size_t BIGPK = (size_t)32 * 256 * 64 * 8 * 2;  // 8.39 MB each
  const size_t HHIST = (size_t)NTT * NB * NH * 2;      // 33.55 MB per layer
  u16* whh1p  = (u16*)alloc(BIGPK);
  u16* whh2p  = (u16*)alloc(BIGPK);
  u16* whh3p  = (u16*)alloc(BIGPK);
  u16* wih2p  = (u16*)alloc(BIGPK);
  u16* wih3p  = (u16*)alloc(BIGPK);
  u16* wfusep = (u16*)alloc(BIGPK);
  u16* wih1p  = (u16*)alloc((size_t)6 * 256 * 64 * 8 * 2);
  u16* wdecp  = (u16*)alloc((size_t)32 * 11 * 64 * 8 * 2);
  u16* seedp  = (u16*)alloc((size_t)NSEED * NB * NINP * 2);
  u16* h1h    = (u16*)alloc(HHIST);                    // write-once per (t)
  u16* h2h    = (u16*)alloc(HHIST);                    // write-once per (t)
  u16* h3h    = (u16*)alloc(HHIST);                    // write-once per (t)
  float* b1s  = (float*)alloc((size_t)NG * 4);
  float* b1g  = (float*)alloc((size_t)NG * 4);
  float* b2   = (float*)alloc((size_t)NG * 4);
  float* b3   = (float*)alloc((size_t)NG * 4);
  float* bdecp = (float*)alloc((size_t)NOUTP * 4);
  int* flags  = (int*)alloc((size_t)NWG * 4);
  // Wfuse fp32 temp aliases h3h (prep finishes before lstm_main writes h3h,
  // and lstm_main fully rewrites h3h before any in-kernel/dec read of it).
  float* wftmp = (float*)h3h;

  // ---- prep ----
  pack_mat<<<dim3(2048), dim3(256), 0, stream>>>(Whh1, whh1p, 32);
  pack_mat<<<dim3(2048), dim3(256), 0, stream>>>(Whh2, whh2p, 32);
  pack_mat<<<dim3(2048), dim3(256), 0, stream>>>(Whh3, whh3p, 32);
  pack_mat<<<dim3(2048), dim3(256), 0, stream>>>(Wih2, wih2p, 32);
  pack_mat<<<dim3(2048), dim3(256), 0, stream>>>(Wih3, wih3p, 32);
  pack_wih1<<<dim3(384), dim3(256), 0, stream>>>(Wih1, wih1p);
  wfuse_kernel<<<dim3(4096, 4), dim3(256), 0, stream>>>(Wih1, Wdec, wftmp);
  pack_mat<<<dim3(2048), dim3(256), 0, stream>>>(wftmp, wfusep, 32);
  pack_wdec<<<dim3(88), dim3(256), 0, stream>>>(Wdec, wdecp);
  pack_seed<<<dim3(3072), dim3(256), 0, stream>>>(seed, seedp);
  prep_bias<<<dim3(16), dim3(256), 0, stream>>>(bih1, bhh1, bih2, bhh2, bih3, bhh3,
                                                Wih1, bdec, b1s, b1g, b2, b3, bdecp, flags);
  // ---- recurrence ----
  lstm_main<<<dim3(NWG), dim3(256), 0, stream>>>(
      whh1p, whh2p, whh3p, wih2p, wih3p, wfusep, wih1p, seedp,
      h1h, h2h, h3h, b1s, b1g, b2, b3, flags);
  // ---- batched decoder ----
  dec_kernel<<<dim3(1408), dim3(256), 0, stream>>>(h3h, wdecp, bdecp, (float*)d_out);
}